// Round 1
// baseline (694.811 us; speedup 1.0000x reference)
//
#include <hip/hip_runtime.h>
#include <stdint.h>

// FP8 E4M3 bit-exact multiply to FP32 bits.
// Inputs: A,B = [N,8] float32 of 0/1 (bits [S,E3..E0,M2..M0]).
// Output: [N,32] float32 of 0/1 (bits [S,E7..E0,M22..M0]).
// Memory-bound: 268 MB read + 537 MB write => ~128 us floor at 6.3 TB/s.
//
// One thread per OUTPUT float4 (4 bits). 8 threads per element (redundant
// decode, trivial VALU) so that every global_store_dwordx4 is a contiguous
// aligned 1 KiB per wave -- the write side (2/3 of traffic) is perfectly
// coalesced. The 8 lanes of one element issue identical load addresses,
// which the TA merges, so read traffic stays exact.

__device__ __forceinline__ uint32_t bit_of(float f) {
    // f is exactly 0.0f (0x00000000) or 1.0f (0x3f800000); bit 23 selects.
    return (__float_as_uint(f) >> 23) & 1u;
}

__device__ __forceinline__ void decode8(const float4 v0, const float4 v1,
                                        uint32_t& s, int& frac, int& exp, int& nz) {
    s = bit_of(v0.x);
    int e = (int)((bit_of(v0.y) << 3) | (bit_of(v0.z) << 2) |
                  (bit_of(v0.w) << 1) |  bit_of(v1.x));
    int m = (int)((bit_of(v1.y) << 2) | (bit_of(v1.z) << 1) | bit_of(v1.w));
    // subnormal normalization: leading one at mantissa bit 2/1/0 ->
    // biased exp 120/119/118, significand shifted to the "1.xxx" slot (8..15)
    int frac_sub = (m >= 4) ? (m << 1) : ((m >= 2) ? (m << 2) : (m << 3));
    int exp_sub  = (m >= 4) ? 120      : ((m >= 2) ? 119      : 118);
    bool normal = (e > 0);
    frac = normal ? (m | 8)    : frac_sub;   // 4-bit significand, leading 1 at bit 3
    exp  = normal ? (e + 120)  : exp_sub;    // biased FP32 exponent
    nz   = ((e | m) != 0) ? 1 : 0;
}

__global__ __launch_bounds__(256) void spike_fp8_mul_kernel(
        const float4* __restrict__ A, const float4* __restrict__ B,
        float4* __restrict__ out, int n_out4) {
    int j = blockIdx.x * blockDim.x + threadIdx.x;   // output float4 index
    if (j >= n_out4) return;
    int elem = j >> 3;    // 8 output float4s per element
    int g    = j & 7;     // which 4-bit group of the 32 output bits

    float4 a0 = A[2 * elem], a1 = A[2 * elem + 1];
    float4 b0 = B[2 * elem], b1 = B[2 * elem + 1];

    uint32_t sa, sb; int fa, ea, fb, eb, nza, nzb;
    decode8(a0, a1, sa, fa, ea, nza);
    decode8(b0, b1, sb, fb, eb, nzb);

    uint32_t sign = sa ^ sb;
    int p = fa * fb;                       // 8-bit product in [64, 225] when nz
    int carry = p >> 7;                    // leading one at bit 7 vs bit 6
    int exp_out = ea + eb - 127 + carry;
    // carry: (p-128)<<16 ; no carry: (p-64)<<17 -- both == (p << (17-carry)) & 0x7fffff
    uint32_t mant = ((uint32_t)p << (17 - carry)) & 0x7fffffu;
    uint32_t bits = (sign << 31) | ((uint32_t)exp_out << 23) | mant;
    if (!(nza & nzb)) bits = sign << 31;   // true zero: keep sign, zero exp/mant

    int sh = 31 - (g << 2);                // bit position of this group's first float
    float4 o;
    o.x = ((bits >> sh)       & 1u) ? 1.0f : 0.0f;
    o.y = ((bits >> (sh - 1)) & 1u) ? 1.0f : 0.0f;
    o.z = ((bits >> (sh - 2)) & 1u) ? 1.0f : 0.0f;
    o.w = ((bits >> (sh - 3)) & 1u) ? 1.0f : 0.0f;
    out[j] = o;                            // contiguous 1 KiB per wave store
}

extern "C" void kernel_launch(void* const* d_in, const int* in_sizes, int n_in,
                              void* d_out, int out_size, void* d_ws, size_t ws_size,
                              hipStream_t stream) {
    const float4* A = (const float4*)d_in[0];
    const float4* B = (const float4*)d_in[1];
    float4* out     = (float4*)d_out;
    int n_out4 = out_size / 4;             // one thread per output float4
    const int block = 256;
    int grid = (n_out4 + block - 1) / block;
    hipLaunchKernelGGL(spike_fp8_mul_kernel, dim3(grid), dim3(block), 0, stream,
                       A, B, out, n_out4);
}

// Round 2
// 672.781 us; speedup vs baseline: 1.0327x; 1.0327x over previous
//
#include <hip/hip_runtime.h>
#include <stdint.h>

// FP8 E4M3 bit-exact multiply to FP32 bits.
// Inputs: A,B = [N,8] float32 of 0/1 (bits [S,E3..E0,M2..M0]).
// Output: [N,32] float32 of 0/1 (bits [S,E7..E0,M22..M0]).
// HBM floor: 268 MB read + 537 MB write => ~128 us at 6.3 TB/s.
//
// One thread per element: reads are exact (no redundancy; the stride-2
// float4 pair per array fully covers its cache lines). The 32 result bits
// are packed in ONE uint32; a wave-level transpose (8 x __shfl broadcast of
// that uint32) lets every store instruction cover a contiguous aligned
// 1 KiB. Bit->float expansion happens after the shuffle, so only 4 B per
// element crosses lanes.

__device__ __forceinline__ uint32_t bit_of(float f) {
    // f is exactly 0.0f (0x00000000) or 1.0f (0x3f800000); bit 23 selects.
    return (__float_as_uint(f) >> 23) & 1u;
}

__device__ __forceinline__ void decode8(const float4 v0, const float4 v1,
                                        uint32_t& s, int& frac, int& exp, int& nz) {
    s = bit_of(v0.x);
    int e = (int)((bit_of(v0.y) << 3) | (bit_of(v0.z) << 2) |
                  (bit_of(v0.w) << 1) |  bit_of(v1.x));
    int m = (int)((bit_of(v1.y) << 2) | (bit_of(v1.z) << 1) | bit_of(v1.w));
    // subnormal normalization: leading one at mantissa bit 2/1/0 ->
    // biased exp 120/119/118, significand shifted to the "1.xxx" slot (8..15)
    int frac_sub = (m >= 4) ? (m << 1) : ((m >= 2) ? (m << 2) : (m << 3));
    int exp_sub  = (m >= 4) ? 120      : ((m >= 2) ? 119      : 118);
    bool normal = (e > 0);
    frac = normal ? (m | 8)   : frac_sub;   // 4-bit significand, leading 1 at bit 3
    exp  = normal ? (e + 120) : exp_sub;    // biased FP32 exponent
    nz   = ((e | m) != 0) ? 1 : 0;
}

__global__ __launch_bounds__(256) void spike_fp8_mul_kernel(
        const float4* __restrict__ A, const float4* __restrict__ B,
        float4* __restrict__ out, int n_elem) {
    int gid  = blockIdx.x * blockDim.x + threadIdx.x;   // element index
    int lane = threadIdx.x & 63;
    int lgid = (gid < n_elem) ? gid : (n_elem - 1);     // clamp: keep full wave for shfl

    float4 a0 = A[2 * lgid], a1 = A[2 * lgid + 1];
    float4 b0 = B[2 * lgid], b1 = B[2 * lgid + 1];

    uint32_t sa, sb; int fa, ea, fb, eb, nza, nzb;
    decode8(a0, a1, sa, fa, ea, nza);
    decode8(b0, b1, sb, fb, eb, nzb);

    uint32_t sign = sa ^ sb;
    int p = fa * fb;                        // 8-bit product in [64, 225] when nz
    int carry = p >> 7;                     // leading one at bit 7 vs bit 6
    int exp_out = ea + eb - 127 + carry;
    // carry: (p-128)<<16 ; no carry: (p-64)<<17 == (p << (17-carry)) & 0x7fffff
    uint32_t mant = ((uint32_t)p << (17 - carry)) & 0x7fffffu;
    uint32_t bits = (sign << 31) | ((uint32_t)exp_out << 23) | mant;
    if (!(nza & nzb)) bits = sign << 31;    // true zero: keep sign, zero exp/mant

    // ---- wave transpose: lane `lane` stores output float4 (i*64 + lane) of
    // this wave's 512-float4 output tile; its source element is the lane
    // i*8 + (lane>>3), its bit group is (lane&7). ----
    int we = gid - lane;                    // wave's first element
    float4* wout = out + (size_t)we * 8;
    int g   = lane & 7;
    int src = lane >> 3;
    uint32_t m0 = 1u << (31 - (g << 2));
    uint32_t m1 = m0 >> 1, m2 = m0 >> 2, m3 = m0 >> 3;
    long long lim = (long long)n_elem * 8; // output float4 count

    #pragma unroll
    for (int i = 0; i < 8; ++i) {
        uint32_t ub = (uint32_t)__shfl((int)bits, i * 8 + src, 64);
        float4 o;
        o.x = (ub & m0) ? 1.0f : 0.0f;
        o.y = (ub & m1) ? 1.0f : 0.0f;
        o.z = (ub & m2) ? 1.0f : 0.0f;
        o.w = (ub & m3) ? 1.0f : 0.0f;
        long long j = (long long)we * 8 + i * 64 + lane;
        if (j < lim) wout[i * 64 + lane] = o;   // contiguous 1 KiB per wave
    }
}

extern "C" void kernel_launch(void* const* d_in, const int* in_sizes, int n_in,
                              void* d_out, int out_size, void* d_ws, size_t ws_size,
                              hipStream_t stream) {
    const float4* A = (const float4*)d_in[0];
    const float4* B = (const float4*)d_in[1];
    float4* out     = (float4*)d_out;
    int n_elem = in_sizes[0] / 8;          // one thread per element
    const int block = 256;
    int grid = (n_elem + block - 1) / block;
    hipLaunchKernelGGL(spike_fp8_mul_kernel, dim3(grid), dim3(block), 0, stream,
                       A, B, out, n_elem);
}

// Round 4
// 671.907 us; speedup vs baseline: 1.0341x; 1.0013x over previous
//
#include <hip/hip_runtime.h>
#include <stdint.h>

// FP8 E4M3 bit-exact multiply to FP32 bits.
// Inputs: A,B = [N,8] float32 of 0/1 (bits [S,E3..E0,M2..M0]).
// Output: [N,32] float32 of 0/1 (bits [S,E7..E0,M22..M0]).
// HBM floor: 268 MB read + 537 MB write => ~128 us at 6.3 TB/s.
//
// One thread per TWO elements (more MLP per wave). The 32 result bits per
// element are packed in one uint32; a wave-level transpose (__shfl
// broadcast) makes every store a contiguous aligned 1 KiB per wave.
// All streams are touch-once, so loads and stores use the `nt`
// (non-temporal) cache hint to keep the 537 MB write stream and the
// 268 MB read stream from thrashing each other in the 32 MB L2.
//
// NOTE: __builtin_nontemporal_* requires a NATIVE vector type, not HIP's
// HIP_vector_type struct -- hence nfloat4 (same size/alignment/layout).

typedef float nfloat4 __attribute__((ext_vector_type(4)));

__device__ __forceinline__ uint32_t bit_of(float f) {
    // f is exactly 0.0f (0x00000000) or 1.0f (0x3f800000); bit 23 selects.
    return (__float_as_uint(f) >> 23) & 1u;
}

__device__ __forceinline__ void decode8(const nfloat4 v0, const nfloat4 v1,
                                        uint32_t& s, int& frac, int& exp, int& nz) {
    s = bit_of(v0.x);
    int e = (int)((bit_of(v0.y) << 3) | (bit_of(v0.z) << 2) |
                  (bit_of(v0.w) << 1) |  bit_of(v1.x));
    int m = (int)((bit_of(v1.y) << 2) | (bit_of(v1.z) << 1) | bit_of(v1.w));
    // subnormal normalization: leading one at mantissa bit 2/1/0 ->
    // biased exp 120/119/118, significand shifted to the "1.xxx" slot (8..15)
    int frac_sub = (m >= 4) ? (m << 1) : ((m >= 2) ? (m << 2) : (m << 3));
    int exp_sub  = (m >= 4) ? 120      : ((m >= 2) ? 119      : 118);
    bool normal = (e > 0);
    frac = normal ? (m | 8)   : frac_sub;   // 4-bit significand, leading 1 at bit 3
    exp  = normal ? (e + 120) : exp_sub;    // biased FP32 exponent
    nz   = ((e | m) != 0) ? 1 : 0;
}

__device__ __forceinline__ uint32_t mul_bits(const nfloat4 a0, const nfloat4 a1,
                                             const nfloat4 b0, const nfloat4 b1) {
    uint32_t sa, sb; int fa, ea, fb, eb, nza, nzb;
    decode8(a0, a1, sa, fa, ea, nza);
    decode8(b0, b1, sb, fb, eb, nzb);
    uint32_t sign = sa ^ sb;
    int p = fa * fb;                        // 8-bit product in [64, 225] when nz
    int carry = p >> 7;                     // leading one at bit 7 vs bit 6
    int exp_out = ea + eb - 127 + carry;
    // carry: (p-128)<<16 ; no carry: (p-64)<<17 == (p << (17-carry)) & 0x7fffff
    uint32_t mant = ((uint32_t)p << (17 - carry)) & 0x7fffffu;
    uint32_t bits = (sign << 31) | ((uint32_t)exp_out << 23) | mant;
    if (!(nza & nzb)) bits = sign << 31;    // true zero: keep sign, zero exp/mant
    return bits;
}

// Grid covers n_elem/2; thread t handles elements (wbase + k*64 + lane)
// for k in {0,1} -- two full consecutive wave-tiles, so the transpose logic
// per tile is identical to the 1-elem version.
__global__ __launch_bounds__(256) void spike_fp8_mul_kernel(
        const nfloat4* __restrict__ A, const nfloat4* __restrict__ B,
        nfloat4* __restrict__ out, int n_elem) {
    int tid  = blockIdx.x * blockDim.x + threadIdx.x;
    int lane = threadIdx.x & 63;
    int wbase = (tid - lane) * 2;           // first element of this wave's 128

    uint32_t bits[2];
    #pragma unroll
    for (int k = 0; k < 2; ++k) {
        int e = wbase + k * 64 + lane;
        int le = (e < n_elem) ? e : (n_elem - 1);   // clamp, keep full wave
        nfloat4 a0 = __builtin_nontemporal_load(A + 2 * le);
        nfloat4 a1 = __builtin_nontemporal_load(A + 2 * le + 1);
        nfloat4 b0 = __builtin_nontemporal_load(B + 2 * le);
        nfloat4 b1 = __builtin_nontemporal_load(B + 2 * le + 1);
        bits[k] = mul_bits(a0, a1, b0, b1);
    }

    // ---- wave transpose per 64-element tile: lane stores output float4
    // (i*64 + lane); source element within tile = i*8 + (lane>>3), bit group
    // g = lane&7. ----
    int g   = lane & 7;
    int src = lane >> 3;
    uint32_t m0 = 1u << (31 - (g << 2));
    uint32_t m1 = m0 >> 1, m2 = m0 >> 2, m3 = m0 >> 3;
    long long lim = (long long)n_elem * 8;  // output float4 count

    #pragma unroll
    for (int k = 0; k < 2; ++k) {
        nfloat4* wout = out + (size_t)(wbase + k * 64) * 8;
        #pragma unroll
        for (int i = 0; i < 8; ++i) {
            uint32_t ub = (uint32_t)__shfl((int)bits[k], i * 8 + src, 64);
            nfloat4 o;
            o.x = (ub & m0) ? 1.0f : 0.0f;
            o.y = (ub & m1) ? 1.0f : 0.0f;
            o.z = (ub & m2) ? 1.0f : 0.0f;
            o.w = (ub & m3) ? 1.0f : 0.0f;
            long long j = (long long)(wbase + k * 64) * 8 + i * 64 + lane;
            if (j < lim)
                __builtin_nontemporal_store(o, wout + i * 64 + lane);  // 1 KiB/wave
        }
    }
}

extern "C" void kernel_launch(void* const* d_in, const int* in_sizes, int n_in,
                              void* d_out, int out_size, void* d_ws, size_t ws_size,
                              hipStream_t stream) {
    const nfloat4* A = (const nfloat4*)d_in[0];
    const nfloat4* B = (const nfloat4*)d_in[1];
    nfloat4* out     = (nfloat4*)d_out;
    int n_elem = in_sizes[0] / 8;
    const int block = 256;
    int n_thread = (n_elem + 1) / 2;        // two elements per thread
    int grid = (n_thread + block - 1) / block;
    hipLaunchKernelGGL(spike_fp8_mul_kernel, dim3(grid), dim3(block), 0, stream,
                       A, B, out, n_elem);
}